// Round 15
// baseline (153.487 us; speedup 1.0000x reference)
//
#include <hip/hip_runtime.h>
#include <math.h>

// LocalEnergyOpt R15: fused halves + register demux of a pure-coalesced
// coord stream.
// Ledger: never byte-bound (FETCH 45-310MB at same ~40-55us, VALUBusy<15%).
// Binding: L1 line transactions + exposed latency. R11 window loads = 4x
// line redundancy (~14K L1 txn/CU); R8 coalesced demux = 1x lines but 20
// serial barriers @ 1 block/CU. R15: coalesced f4 stream, <=1 coord float
// per f4 (col5 = float 5 mod 9) extracted IN REGISTERS (e=(14-(4q)%9)%9,
// e<4), scattered to f4-padded LDS; ONE barrier; all types via per-thread
// scattered reg loads issued first (R12/R13-validated; type lines in the
// coord region are free). 2 term-halves/system -> 512 blocks x 512 thr =
// 2 read streams/CU. Structural arange connectivity + trig-free math
// (absmax 0 across R9-R14). Partials -> d_ws -> tiny reduce.

constexpr int NBT = 50, NAT = 100, NTT = 200;
constexpr float EPS = 1e-8f;

__device__ __forceinline__ float acos_fast(float x) {
    // Abramowitz-Stegun 4.4.45, |err|<=6.8e-5 rad (validated R9-R14, absmax 0)
    float t = fabsf(x);
    float p = fmaf(t, -0.0187293f, 0.0742610f);
    p = fmaf(p, t, -0.2121144f);
    p = fmaf(p, t, 1.5707288f);
    float r = sqrtf(1.0f - t) * p;
    return (x >= 0.0f) ? r : (3.14159265358979f - r);
}

__global__ __launch_bounds__(512) void partial_kernel(
    const float* __restrict__ features,   // [B, 10000, 9]
    const int*   __restrict__ lengths,    // [B, 9]
    const float* __restrict__ opt_pars,   // [350, 3]
    const float* __restrict__ bond_type,  // [50]
    const float* __restrict__ angle_type, // [100]
    const float* __restrict__ tor_type,   // [200]
    float*       __restrict__ part)       // [B*2]
{
    __shared__ float scf[1004 * 4];      // atoms [1000s,1000s+1004) f4-padded
    __shared__ float rbp[2 * NBT];       // (k, r0)
    __shared__ float rap[2 * NAT];       // (k, th0)
    __shared__ float rtp[4 * NTT];       // (k, cos p0, sin p0, n)
    __shared__ float sw[8];

    const int blk = blockIdx.x;
    const int b   = blk >> 1;
    const int s   = blk & 1;
    const int tid = threadIdx.x;
    const float* __restrict__ fb = features + (size_t)b * 90000;

    const int nb = lengths[b * 9 + 6] / 3;
    const int na = lengths[b * 9 + 7] / 4;
    const int nt = lengths[b * 9 + 8] / 5;

    // ---- per-term type loads into regs, issued FIRST (fly under staging)
    //      bond type @ float 27t+24, angle @ 36a+34, torsion @ 45t+44 ----
    const int t0 = 1000 * s + tid;                 // [1000s, 1000s+512)
    const bool h1 = (tid + 512) < 1000;            // second term this half?
    const int t1 = h1 ? (t0 + 512) : t0;           // clamped (guarded at use)
    float bty0 = fb[27 * t0 + 24];
    float aty0 = fb[36 * t0 + 34];
    float tty0 = fb[45 * t0 + 44];
    float bty1 = fb[27 * t1 + 24];
    float aty1 = fb[36 * t1 + 34];
    float tty1 = fb[45 * t1 + 44];

    // ---- resolved param tables ----
    if (tid < NBT) {
        int idx = (int)bond_type[tid];
        rbp[2*tid+0] = opt_pars[3*idx+0];
        rbp[2*tid+1] = opt_pars[3*idx+1];
    } else if (tid < NBT + NAT) {
        int i = tid - NBT;
        int idx = (int)angle_type[i];
        rap[2*i+0] = opt_pars[3*idx+0];
        rap[2*i+1] = opt_pars[3*idx+1];
    } else if (tid < NBT + NAT + NTT) {
        int i = tid - NBT - NAT;
        int idx = (int)tor_type[i];
        float p0 = opt_pars[3*idx+1];
        rtp[4*i+0] = opt_pars[3*idx+0];
        rtp[4*i+1] = cosf(p0);
        rtp[4*i+2] = sinf(p0);
        rtp[4*i+3] = opt_pars[3*idx+2];
    }

    // ---- coalesced f4 stream over coord rows [3000s, 3000s+nrows),
    //      register demux: f4 q holds coord float iff (4q)%9 -> e<4 ----
    {
        const float4* __restrict__ fv4 = (const float4*)fb;
        const unsigned q0    = 6750u * s;
        const unsigned qn    = s ? 6750u : 6777u;
        const unsigned fbase = 3000u * s;
        const unsigned frng  = s ? 3000u : 3012u;
        #pragma unroll
        for (int k = 0; k < 14; ++k) {
            const unsigned lq = tid + 512u * k;
            if (lq < qn) {
                float4 v = fv4[q0 + lq];
                const unsigned g = 4u * (q0 + lq);        // global float idx
                const unsigned m = g % 9u;
                const unsigned e = (14u - m) % 9u;        // lane of col-5 float
                if (e < 4u) {
                    const unsigned f = (g + e - 5u) / 9u; // flat coord index
                    const unsigned la3 = f - fbase;
                    if (la3 < frng && f < 6000u) {
                        float val = (e == 0u) ? v.x : (e == 1u) ? v.y
                                  : (e == 2u) ? v.z : v.w;
                        const unsigned la = la3 / 3u, d = la3 - 3u * la;
                        scf[4u * la + d] = val;
                    }
                }
            }
        }
    }
    __syncthreads();

    const float4* __restrict__ sc4 = (const float4*)scf;

    auto bond_e = [&](int la, int ty) -> float {
        float4 pi = sc4[la], pj = sc4[la + 1];
        float dx = pi.x - pj.x, dy = pi.y - pj.y, dz = pi.z - pj.z;
        float r  = sqrtf(dx*dx + dy*dy + dz*dz + EPS);
        float d  = r - rbp[2*ty+1];
        return rbp[2*ty+0] * d * d;
    };
    auto angle_e = [&](int la, int ty) -> float {
        float4 pi = sc4[la], pj = sc4[la + 1], pk = sc4[la + 2];
        float ux = pi.x - pj.x, uy = pi.y - pj.y, uz = pi.z - pj.z;
        float vx = pk.x - pj.x, vy = pk.y - pj.y, vz = pk.z - pj.z;
        float uv = ux*vx + uy*vy + uz*vz;
        float uu = ux*ux + uy*uy + uz*uz;
        float vv = vx*vx + vy*vy + vz*vz;
        float cth = uv * rsqrtf((uu + EPS) * (vv + EPS));
        cth = fminf(fmaxf(cth, -1.0f + 1e-6f), 1.0f - 1e-6f);
        float d = acos_fast(cth) - rap[2*ty+1];
        return rap[2*ty+0] * d * d;
    };
    auto tor_e = [&](int la, int ty) -> float {
        float4 pi = sc4[la], pj = sc4[la+1], pk = sc4[la+2], pl = sc4[la+3];
        float b1x = pj.x - pi.x, b1y = pj.y - pi.y, b1z = pj.z - pi.z;
        float b2x = pk.x - pj.x, b2y = pk.y - pj.y, b2z = pk.z - pj.z;
        float b3x = pl.x - pk.x, b3y = pl.y - pk.y, b3z = pl.z - pk.z;
        float n1x = b1y*b2z - b1z*b2y;
        float n1y = b1z*b2x - b1x*b2z;
        float n1z = b1x*b2y - b1y*b2x;
        float n2x = b2y*b3z - b2z*b3y;
        float n2y = b2z*b3x - b2x*b3z;
        float n2z = b2x*b3y - b2y*b3x;
        float inv = rsqrtf(b2x*b2x + b2y*b2y + b2z*b2z + EPS);
        float hx = b2x * inv, hy = b2y * inv, hz = b2z * inv;
        float m1x = n1y*hz - n1z*hy;
        float m1y = n1z*hx - n1x*hz;
        float m1z = n1x*hy - n1y*hx;
        float sy = m1x*n2x + m1y*n2y + m1z*n2z;   // |n1||n2| sin(phi)
        float sx = n1x*n2x + n1y*n2y + n1z*n2z;   // |n1||n2| cos(phi)
        float rinv = rsqrtf(sx*sx + sy*sy + 1e-30f);
        float c1 = sx * rinv, s1 = sy * rinv;
        float c2 = fmaf(2.0f*c1, c1, -1.0f);
        float s2 = 2.0f * s1 * c1;
        float c3 = fmaf(2.0f*c1, c2, -c1);
        float s3 = fmaf(2.0f*c1, s2, -s1);
        float k  = rtp[4*ty+0];
        float cp = rtp[4*ty+1];
        float sp = rtp[4*ty+2];
        int   ni = (int)rtp[4*ty+3];
        float cn = (ni == 1) ? c1 : ((ni == 2) ? c2 : c3);
        float sn = (ni == 1) ? s1 : ((ni == 2) ? s2 : s3);
        return k * (1.0f + cn * cp + sn * sp);
    };

    float acc = 0.0f;
    const int la0 = tid;            // t0 - 1000s
    const int la1 = tid + 512;      // t1 - 1000s (valid iff h1)
    {
        float e0 = (t0 < nb) ? bond_e(la0, (int)bty0) : 0.0f;
        float e1 = (h1 && t1 < nb) ? bond_e(la1, (int)bty1) : 0.0f;
        acc += e0 + e1;
    }
    {
        float e0 = (t0 < na) ? angle_e(la0, (int)aty0) : 0.0f;
        float e1 = (h1 && t1 < na) ? angle_e(la1, (int)aty1) : 0.0f;
        acc += e0 + e1;
    }
    {
        float e0 = (t0 < nt) ? tor_e(la0, (int)tty0) : 0.0f;
        float e1 = (h1 && t1 < nt) ? tor_e(la1, (int)tty1) : 0.0f;
        acc += e0 + e1;
    }

    // ---- block reduce (8 waves) -> part[blk] ----
    for (int off = 32; off > 0; off >>= 1)
        acc += __shfl_down(acc, off, 64);
    const int wave = tid >> 6, lane = tid & 63;
    if (lane == 0) sw[wave] = acc;
    __syncthreads();
    if (tid == 0) {
        float v = 0.0f;
        #pragma unroll
        for (int w = 0; w < 8; ++w) v += sw[w];
        part[blk] = v;
    }
}

__global__ __launch_bounds__(256) void reduce_kernel(
    const float* __restrict__ part, float* __restrict__ out)
{
    const int b = threadIdx.x;
    out[b] = part[2*b] + part[2*b+1];
}

extern "C" void kernel_launch(void* const* d_in, const int* in_sizes, int n_in,
                              void* d_out, int out_size, void* d_ws, size_t ws_size,
                              hipStream_t stream) {
    const float* features   = (const float*)d_in[0];
    const int*   lengths    = (const int*)  d_in[1];
    const float* opt_pars   = (const float*)d_in[2];
    const float* bond_type  = (const float*)d_in[3];
    const float* angle_type = (const float*)d_in[4];
    const float* tor_type   = (const float*)d_in[5];
    float* out  = (float*)d_out;
    float* part = (float*)d_ws;

    const int B = out_size;  // 256
    partial_kernel<<<B * 2, 512, 0, stream>>>(
        features, lengths, opt_pars, bond_type, angle_type, tor_type, part);
    reduce_kernel<<<1, 256, 0, stream>>>(part, out);
}

// Round 16
// 142.870 us; speedup vs baseline: 1.0743x; 1.0743x over previous
//
#include <hip/hip_runtime.h>
#include <math.h>

// LocalEnergyOpt R16 == R11 (empirical best, 144.3 us bench, ~39 us kernel).
// Restored after R12-R15 all regressed (146-153 us): fetch reduction,
// slicing, full coalescing+demux, and register-demux each lost to this
// structure. Ledger conclusion: ~39 us = ~92 MB mandatory line fetches at
// the ~2.4-3.3 TB/s effective read rate this access mix sustains, plus
// dependent-gather tails; occupancy/coalescing/byte-count levers are all
// empirically falsified on this part.
// Structure: fused, 1 block/system (grid 256), 1024 threads. Phase A stages
// rows [0,6000) (coords+bonds+78% of angle/torsion rows) via 4-dword window
// loads (row i -> floats 9i+5..9i+8); phase-B loads (rows >= 6000) are
// issued into registers BEFORE group-1 compute so their latency hides under
// it; regs->LDS; barrier; group-2. Compute: f4-padded coord LDS
// (ds_read_b128), manual 2x term unroll (ILP), trig-free torsions
// (Chebyshev + precomputed cos/sin p0), poly acos (absmax 0 since R9).

#define EBS 1024

constexpr int MAXLEN = 10000;
constexpr int NBT = 50, NAT = 100, NTT = 200;
constexpr float EPS = 1e-8f;

// LDS layout (bytes) — 88464 B -> 1 block/CU
constexpr int OFF_SCF = 0;                     // 2000 atoms * float4 (x,y,z,-)
constexpr int OFF_SB  = OFF_SCF + 8000 * 4;    // 2000 * ushort4 bonds (i,j,ty,-)
constexpr int OFF_SA  = OFF_SB  + 8000 * 2;    // 7992 u16 angles, natural 4/term
constexpr int OFF_ST4 = OFF_SA  + 8000 * 2;    // 2000 * ushort4 torsion ijkl
constexpr int OFF_STY = OFF_ST4 + 8000 * 2;    // 2000 u16 torsion type
constexpr int OFF_RBP = OFF_STY + 2000 * 2;    // 50*(k,r0)
constexpr int OFF_RAP = OFF_RBP + 100 * 4;     // 100*(k,th0)
constexpr int OFF_RTP = OFF_RAP + 200 * 4;     // 200*(k,cp,sp,n)
constexpr int OFF_SW  = OFF_RTP + 800 * 4;     // 16 f32 wave partials
constexpr int SMEM_BYTES = OFF_SW + 16 * 4;

__device__ __forceinline__ float acos_fast(float x) {
    // Abramowitz-Stegun 4.4.45, |err|<=6.8e-5 rad (absmax 0 across R9-R15)
    float t = fabsf(x);
    float p = fmaf(t, -0.0187293f, 0.0742610f);
    p = fmaf(p, t, -0.2121144f);
    p = fmaf(p, t, 1.5707288f);
    float r = sqrtf(1.0f - t) * p;
    return (x >= 0.0f) ? r : (3.14159265358979f - r);
}

__global__ __launch_bounds__(EBS) void energy_kernel(
    const float* __restrict__ features,   // [B, 10000, 9]
    const int*   __restrict__ lengths,    // [B, 9]
    const float* __restrict__ opt_pars,   // [350, 3]
    const float* __restrict__ bond_type,  // [50]
    const float* __restrict__ angle_type, // [100]
    const float* __restrict__ tor_type,   // [200]
    float*       __restrict__ out)        // [B]
{
    extern __shared__ __align__(16) char smem[];
    float*          scf = (float*)(smem + OFF_SCF);
    const float4*   sc4 = (const float4*)(smem + OFF_SCF);
    unsigned short* sb  = (unsigned short*)(smem + OFF_SB);
    const ushort4*  sb4 = (const ushort4*)(smem + OFF_SB);
    unsigned short* sa  = (unsigned short*)(smem + OFF_SA);
    const ushort4*  sa4 = (const ushort4*)(smem + OFF_SA);
    unsigned short* st4 = (unsigned short*)(smem + OFF_ST4);
    const ushort4*  st44= (const ushort4*)(smem + OFF_ST4);
    unsigned short* sty = (unsigned short*)(smem + OFF_STY);
    float*          rbp = (float*)(smem + OFF_RBP);
    float*          rap = (float*)(smem + OFF_RAP);
    float*          rtp = (float*)(smem + OFF_RTP);
    float*          sw  = (float*)(smem + OFF_SW);

    const int b   = blockIdx.x;
    const int tid = threadIdx.x;
    const float* __restrict__ fb = features + (size_t)b * MAXLEN * 9;

    // ---- resolved param tables ----
    if (tid < NBT) {
        int idx = (int)bond_type[tid];
        rbp[2*tid+0] = opt_pars[3*idx+0];
        rbp[2*tid+1] = opt_pars[3*idx+1];
    } else if (tid < NBT + NAT) {
        int i = tid - NBT;
        int idx = (int)angle_type[i];
        rap[2*i+0] = opt_pars[3*idx+0];
        rap[2*i+1] = opt_pars[3*idx+1];
    } else if (tid < NBT + NAT + NTT) {
        int i = tid - NBT - NAT;
        int idx = (int)tor_type[i];
        float p0 = opt_pars[3*idx+1];
        rtp[4*i+0] = opt_pars[3*idx+0];
        rtp[4*i+1] = cosf(p0);
        rtp[4*i+2] = sinf(p0);
        rtp[4*i+3] = opt_pars[3*idx+2];
    }

    // ---- Phase A: stage rows [0,6000) — coords(all) + bonds(all) +
    //      angle rows<6000 (t<1500) + torsion rows<6000 (t<1200) ----
    #pragma unroll
    for (int k = 0; k < 6; ++k) {
        const int i = tid + k * EBS;
        if (i < 6000) {
            const float* __restrict__ row = fb + 9 * i + 5;
            float vc = row[0];
            float vb = row[1];
            float va = row[2];
            float vt = row[3];
            const int q3 = i / 3, r3 = i - 3 * q3;      // atom / dim; bond t / slot
            scf[4 * q3 + r3] = vc;
            if (i < 5997) sb[4 * q3 + r3] = (unsigned short)(int)vb;
            sa[i] = (unsigned short)(int)va;            // i < 6000 < 7992
            const int q5 = i / 5, r5 = i - 5 * q5;
            if (r5 < 4) st4[4 * q5 + r5] = (unsigned short)(int)vt;
            else        sty[q5]          = (unsigned short)(int)vt;
        }
    }
    __syncthreads();

    const int nb = lengths[b * 9 + 6] / 3;
    const int na = lengths[b * 9 + 7] / 4;
    const int nt = lengths[b * 9 + 8] / 5;

    // ---- term bodies (read LDS only) ----
    auto bond_e = [&](int t) -> float {
        ushort4 q = sb4[t];
        float4 pi = sc4[q.x], pj = sc4[q.y];
        float dx = pi.x - pj.x, dy = pi.y - pj.y, dz = pi.z - pj.z;
        float r  = sqrtf(dx*dx + dy*dy + dz*dz + EPS);
        float d  = r - rbp[2*q.z+1];
        return rbp[2*q.z+0] * d * d;
    };
    auto angle_e = [&](int t) -> float {
        ushort4 q = sa4[t];
        float4 pi = sc4[q.x], pj = sc4[q.y], pk = sc4[q.z];
        float ux = pi.x - pj.x, uy = pi.y - pj.y, uz = pi.z - pj.z;
        float vx = pk.x - pj.x, vy = pk.y - pj.y, vz = pk.z - pj.z;
        float uv = ux*vx + uy*vy + uz*vz;
        float uu = ux*ux + uy*uy + uz*uz;
        float vv = vx*vx + vy*vy + vz*vz;
        float cth = uv * rsqrtf((uu + EPS) * (vv + EPS));
        cth = fminf(fmaxf(cth, -1.0f + 1e-6f), 1.0f - 1e-6f);
        float d = acos_fast(cth) - rap[2*q.w+1];
        return rap[2*q.w+0] * d * d;
    };
    auto tor_e = [&](int t) -> float {
        ushort4 q = st44[t];
        int ty = sty[t];
        float4 pi = sc4[q.x], pj = sc4[q.y], pk = sc4[q.z], pl = sc4[q.w];
        float b1x = pj.x - pi.x, b1y = pj.y - pi.y, b1z = pj.z - pi.z;
        float b2x = pk.x - pj.x, b2y = pk.y - pj.y, b2z = pk.z - pj.z;
        float b3x = pl.x - pk.x, b3y = pl.y - pk.y, b3z = pl.z - pk.z;
        float n1x = b1y*b2z - b1z*b2y;
        float n1y = b1z*b2x - b1x*b2z;
        float n1z = b1x*b2y - b1y*b2x;
        float n2x = b2y*b3z - b2z*b3y;
        float n2y = b2z*b3x - b2x*b3z;
        float n2z = b2x*b3y - b2y*b3x;
        float inv = rsqrtf(b2x*b2x + b2y*b2y + b2z*b2z + EPS);
        float hx = b2x * inv, hy = b2y * inv, hz = b2z * inv;
        float m1x = n1y*hz - n1z*hy;
        float m1y = n1z*hx - n1x*hz;
        float m1z = n1x*hy - n1y*hx;
        float sy = m1x*n2x + m1y*n2y + m1z*n2z;   // |n1||n2| sin(phi)
        float sx = n1x*n2x + n1y*n2y + n1z*n2z;   // |n1||n2| cos(phi)
        float rinv = rsqrtf(sx*sx + sy*sy + 1e-30f);
        float c1 = sx * rinv, s1 = sy * rinv;
        float c2 = fmaf(2.0f*c1, c1, -1.0f);
        float s2 = 2.0f * s1 * c1;
        float c3 = fmaf(2.0f*c1, c2, -c1);
        float s3 = fmaf(2.0f*c1, s2, -s1);
        float k  = rtp[4*ty+0];
        float cp = rtp[4*ty+1];
        float sp = rtp[4*ty+2];
        int   ni = (int)rtp[4*ty+3];
        float cn = (ni == 1) ? c1 : ((ni == 2) ? c2 : c3);
        float sn = (ni == 1) ? s1 : ((ni == 2) ? s2 : s3);
        return k * (1.0f + cn * cp + sn * sp);
    };

    float acc = 0.0f;

    // ---- Phase B loads (rows [6000,10000), cols 7+8) issued here so the
    //      compiler overlaps them with group-1 compute below ----
    float pva[4], pvt[4];
    #pragma unroll
    for (int k = 0; k < 4; ++k) {
        const int i = 6000 + tid + k * EBS;
        if (i < MAXLEN) {
            const float* __restrict__ row = fb + 9 * i + 7;
            pva[k] = row[0];
            pvt[k] = row[1];
        }
    }

    // ---- group-1 compute: bonds(all) + angles t<1500 + tors t<1200 ----
    {
        int t0 = tid, t1 = tid + EBS;              // independent -> ILP
        float e0 = (t0 < nb) ? bond_e(t0) : 0.0f;
        float e1 = (t1 < nb) ? bond_e(t1) : 0.0f;
        acc += e0 + e1;
    }
    {
        const int lim = min(na, 1500);
        int t0 = tid, t1 = tid + EBS;
        float e0 = (t0 < lim) ? angle_e(t0) : 0.0f;
        float e1 = (t1 < lim) ? angle_e(t1) : 0.0f;
        acc += e0 + e1;
    }
    {
        const int lim = min(nt, 1200);
        int t0 = tid, t1 = tid + EBS;
        float e0 = (t0 < lim) ? tor_e(t0) : 0.0f;
        float e1 = (t1 < lim) ? tor_e(t1) : 0.0f;
        acc += e0 + e1;
    }

    // ---- Phase B write-back regs -> LDS ----
    #pragma unroll
    for (int k = 0; k < 4; ++k) {
        const int i = 6000 + tid + k * EBS;
        if (i < MAXLEN) {
            if (i < 7992) sa[i] = (unsigned short)(int)pva[k];
            if (i < 9985) {
                const int q5 = i / 5, r5 = i - 5 * q5;
                if (r5 < 4) st4[4 * q5 + r5] = (unsigned short)(int)pvt[k];
                else        sty[q5]          = (unsigned short)(int)pvt[k];
            }
        }
    }
    __syncthreads();

    // ---- group-2 compute: angles t in [1500,na), tors t in [1200,nt) ----
    {
        int t = 1500 + tid;
        if (t < na) acc += angle_e(t);
        int u = 1200 + tid;
        if (u < nt) acc += tor_e(u);
    }

    // ---- reduce: 64-lane shuffle, then cross-wave via LDS ----
    for (int off = 32; off > 0; off >>= 1)
        acc += __shfl_down(acc, off, 64);
    const int wave = tid >> 6, lane = tid & 63;
    if (lane == 0) sw[wave] = acc;
    __syncthreads();
    if (tid == 0) {
        float v = 0.0f;
        #pragma unroll
        for (int w = 0; w < EBS / 64; ++w) v += sw[w];
        out[b] = v;
    }
}

extern "C" void kernel_launch(void* const* d_in, const int* in_sizes, int n_in,
                              void* d_out, int out_size, void* d_ws, size_t ws_size,
                              hipStream_t stream) {
    const float* features   = (const float*)d_in[0];
    const int*   lengths    = (const int*)  d_in[1];
    const float* opt_pars   = (const float*)d_in[2];
    const float* bond_type  = (const float*)d_in[3];
    const float* angle_type = (const float*)d_in[4];
    const float* tor_type   = (const float*)d_in[5];
    float* out = (float*)d_out;

    // ~86.4 KB dynamic LDS (> 64 KB default); idempotent, capture-safe.
    hipFuncSetAttribute((const void*)energy_kernel,
                        hipFuncAttributeMaxDynamicSharedMemorySize, SMEM_BYTES);

    const int B = out_size;  // 256
    energy_kernel<<<B, EBS, SMEM_BYTES, stream>>>(
        features, lengths, opt_pars, bond_type, angle_type, tor_type, out);
}